// Round 10
// baseline (113.468 us; speedup 1.0000x reference)
//
#include <hip/hip_runtime.h>
#include <hip/hip_bf16.h>
#include <math.h>

#define T_TOKENS 16384
#define DDIM 2048
#define NEXP 64
#define REFINE_TAU 4e-3f
#define KSL 8                      // K slices
#define KPS (DDIM / KSL)           // 256 k per slice
#define NKS (KPS / 32)             // 8 ksteps per slice
#define TOK_TILE 64
#define ITERS (TOK_TILE / 16)      // 4 token-iters per block
#define NBLK1 ((T_TOKENS / TOK_TILE) * KSL)   // 2048 blocks

typedef short bf16x8 __attribute__((ext_vector_type(8)));
typedef float f32x4 __attribute__((ext_vector_type(4)));

__device__ __forceinline__ short bf16hi(float f) {
    __hip_bfloat16 h = __float2bfloat16(f);       // RNE
    return *reinterpret_cast<short*>(&h);
}
__device__ __forceinline__ float bf16up(short s) {
    __hip_bfloat16 h = *reinterpret_cast<__hip_bfloat16*>(&s);
    return __bfloat162float(h);
}

// ---------------- Kernel 0: W -> fragment-ordered panels (hi/lo) ----------------
// Element (expert r, k) -> panel[((g*64 + ks)*64 + lane)*8 + j], g=r>>4,
// ks=k>>5, lane=((k>>3)&3)*16 + (r&15), j=k&7.  (R4-R8-verified B-frag mapping.)
__global__ __launch_bounds__(256)
void prep_w(const float* __restrict__ W, short* __restrict__ ph, short* __restrict__ pl) {
    const int t  = blockIdx.x * 256 + threadIdx.x;   // 0..16383
    const int r  = t >> 8;
    const int kc = (t & 255) * 8;
    const float* wp = &W[(size_t)r * DDIM + kc];
    const float4 a = *(const float4*)wp;
    const float4 b = *(const float4*)(wp + 4);
    const float f[8] = { a.x, a.y, a.z, a.w, b.x, b.y, b.z, b.w };
    bf16x8 h, l;
#pragma unroll
    for (int j = 0; j < 8; ++j) {
        const short hh = bf16hi(f[j]);
        h[j] = hh;
        l[j] = bf16hi(f[j] - bf16up(hh));
    }
    const int g = r >> 4, ks = kc >> 5;
    const int lane = (((kc >> 3) & 3) << 4) + (r & 15);
    const size_t idx = ((((size_t)g * 64 + ks) * 64) + lane) * 8;
    *(bf16x8*)&ph[idx] = h;
    *(bf16x8*)&pl[idx] = l;
}

// ---------------- Kernel 1: panel-in-registers GEMM -> fp32 partial logits ----------------
// grid: (256 token-tiles) x (8 K-slices). Block: 256 thr = 4 waves, each wave
// owns 16 experts (full panel slice in 64 VGPRs). x staged per 16-token iter
// into XOR-swizzled bf16 hi/lo LDS; frags via ds_read_b128.
__global__ __launch_bounds__(256)
void gate_partial(const float* __restrict__ x,
                  const short* __restrict__ ph,
                  const short* __restrict__ pl,
                  float* __restrict__ part) {
    __shared__ short xh[2][16 * KPS];   // 8 KB per buffer
    __shared__ short xl[2][16 * KPS];   // total 32 KB

    const int tid   = threadIdx.x;
    const int lane  = tid & 63;
    const int w     = tid >> 6;          // expert group 0..3
    const int bx    = blockIdx.x;
    const int slice = bx & 7;
    const int tokb  = (bx >> 3) * TOK_TILE;

    // ---- panel slice -> registers (once per block; coalesced 1KB/instr) ----
    bf16x8 pv[NKS][2];
#pragma unroll
    for (int ks = 0; ks < NKS; ++ks) {
        const size_t ib = (((size_t)w * 64 + slice * NKS + ks) * 64 + lane) * 8;
        pv[ks][0] = *(const bf16x8*)&ph[ib];
        pv[ks][1] = *(const bf16x8*)&pl[ib];
    }

    // ---- x staging map: thread -> (row = tid>>4, 16 consecutive floats) ----
    const int xr = tid >> 4;             // 0..15
    const int xc = (tid & 15) * 16;      // float col within slice
    const float* xbase = x + (size_t)(tokb + xr) * DDIM + slice * KPS + xc;
    // swizzle applied PER 16B CHUNK (R9 bug: XOR-then-add broke the involution)
    const int swz = ((xr & 7) << 4);
    const int wb0 = ((xr * 512 + (tid & 15) * 32)      ^ swz);
    const int wb1 = ((xr * 512 + (tid & 15) * 32 + 16) ^ swz);

    float4 g0, g1, g2, g3;

#define GLOADX(it) do { \
    const float* p_ = xbase + (size_t)(it) * 16 * DDIM; \
    g0 = *(const float4*)(p_);     g1 = *(const float4*)(p_ + 4); \
    g2 = *(const float4*)(p_ + 8); g3 = *(const float4*)(p_ + 12); \
} while (0)

#define CONVX(buf) do { \
    const float f_[16] = { g0.x, g0.y, g0.z, g0.w, g1.x, g1.y, g1.z, g1.w, \
                           g2.x, g2.y, g2.z, g2.w, g3.x, g3.y, g3.z, g3.w }; \
    bf16x8 h0_, h1_, l0_, l1_; \
    _Pragma("unroll") \
    for (int j_ = 0; j_ < 8; ++j_) { \
        short s_ = bf16hi(f_[j_]); \
        h0_[j_] = s_; l0_[j_] = bf16hi(f_[j_] - bf16up(s_)); \
        s_ = bf16hi(f_[8 + j_]); \
        h1_[j_] = s_; l1_[j_] = bf16hi(f_[8 + j_] - bf16up(s_)); \
    } \
    *(bf16x8*)((char*)xh[buf] + wb0) = h0_; \
    *(bf16x8*)((char*)xh[buf] + wb1) = h1_; \
    *(bf16x8*)((char*)xl[buf] + wb0) = l0_; \
    *(bf16x8*)((char*)xl[buf] + wb1) = l1_; \
} while (0)

    // prologue: stage iter 0
    GLOADX(0);
    CONVX(0);
    __syncthreads();

    float* __restrict__ pout = part + (size_t)slice * T_TOKENS * NEXP;

#pragma unroll
    for (int it = 0; it < ITERS; ++it) {
        if (it + 1 < ITERS) GLOADX(it + 1);          // in flight under compute

        f32x4 acc = { 0.f, 0.f, 0.f, 0.f };
#pragma unroll
        for (int ks = 0; ks < NKS; ++ks) {
            const int ab = (((lane & 15) * 512 + ks * 64 + (lane >> 4) * 16)
                            ^ ((lane & 7) << 4));    // row = lane&15; row&7 == lane&7
            const bf16x8 xhf = *(const bf16x8*)((char*)xh[it & 1] + ab);
            const bf16x8 xlf = *(const bf16x8*)((char*)xl[it & 1] + ab);
            acc = __builtin_amdgcn_mfma_f32_16x16x32_bf16(xhf, pv[ks][0], acc, 0, 0, 0);
            acc = __builtin_amdgcn_mfma_f32_16x16x32_bf16(xhf, pv[ks][1], acc, 0, 0, 0);
            acc = __builtin_amdgcn_mfma_f32_16x16x32_bf16(xlf, pv[ks][0], acc, 0, 0, 0);
        }

        // partial store: row=(lane>>4)*4+j = token-in-tile, col=lane&15 = expert-in-group
#pragma unroll
        for (int j = 0; j < 4; ++j) {
            const int tok = tokb + it * 16 + ((lane >> 4) << 2) + j;
            pout[(size_t)tok * NEXP + w * 16 + (lane & 15)] = acc[j];
        }

        if (it + 1 < ITERS) CONVX((it + 1) & 1);     // vmcnt wait lands here, covered
        __syncthreads();
    }

#undef GLOADX
#undef CONVX
}

// ---------------- Kernel 2: K-reduce + softmax + top-2 (verified epilogue) ----------------
__device__ __forceinline__ bool better(double va, int ia, double vb, int ib) {
    return (va > vb) || (va == vb && ia < ib);
}
__device__ __forceinline__ double dot_f64(const float* __restrict__ xrow,
                                          const float* __restrict__ wr, int lane) {
    double sd = 0.0;
    for (int d = lane; d < DDIM; d += 64)
        sd = fma((double)xrow[d], (double)wr[d], sd);
#pragma unroll
    for (int off = 32; off >= 1; off >>= 1) sd += __shfl_xor(sd, off);
    return sd;
}

__global__ __launch_bounds__(256)
void router_reduce(const float* __restrict__ part,
                   const float* __restrict__ x,
                   const float* __restrict__ W,
                   float* __restrict__ out) {
    const int tid  = threadIdx.x;
    const int lane = tid & 63;
    const int w    = tid >> 6;
    const int tok0 = (blockIdx.x * 4 + w) * 8;

    float* __restrict__ outw = out;
    float* __restrict__ outi = out + (size_t)T_TOKENS * 2;

#pragma unroll 1
    for (int t = 0; t < 8; ++t) {
        const int tok = tok0 + t;
        // fixed-order K reduction (deterministic)
        float l = 0.f;
#pragma unroll
        for (int s = 0; s < KSL; ++s)
            l += part[((size_t)s * T_TOKENS + tok) * NEXP + lane];

        float v1 = l; int i1 = lane;
#pragma unroll
        for (int off = 32; off >= 1; off >>= 1) {
            const float ov = __shfl_xor(v1, off);
            const int   oi = __shfl_xor(i1, off);
            if (ov > v1 || (ov == v1 && oi < i1)) { v1 = ov; i1 = oi; }
        }
        float v2 = (lane == i1) ? -INFINITY : l; int i2 = lane;
#pragma unroll
        for (int off = 32; off >= 1; off >>= 1) {
            const float ov = __shfl_xor(v2, off);
            const int   oi = __shfl_xor(i2, off);
            if (ov > v2 || (ov == v2 && oi < i2)) { v2 = ov; i2 = oi; }
        }
        float v3 = (lane == i1 || lane == i2) ? -INFINITY : l; int i3 = lane;
#pragma unroll
        for (int off = 32; off >= 1; off >>= 1) {
            const float ov = __shfl_xor(v3, off);
            const int   oi = __shfl_xor(i3, off);
            if (ov > v3 || (ov == v3 && oi < i3)) { v3 = ov; i3 = oi; }
        }

        const float p = expf(l - v1);
        float s = p;
#pragma unroll
        for (int off = 32; off >= 1; off >>= 1) s += __shfl_xor(s, off);

        int iA = i1, iB = i2;
        if ((v1 - v2) < REFINE_TAU || (v2 - v3) < REFINE_TAU) {
            const float* __restrict__ xrow = x + (size_t)tok * DDIM;
            double La = dot_f64(xrow, W + (size_t)i1 * DDIM, lane);
            double Lb = dot_f64(xrow, W + (size_t)i2 * DDIM, lane);
            double Lc = dot_f64(xrow, W + (size_t)i3 * DDIM, lane);
            int ia = i1, ib = i2, ic = i3;
            if (!better(La, ia, Lb, ib)) { double tv = La; La = Lb; Lb = tv; int ti = ia; ia = ib; ib = ti; }
            if (!better(Lb, ib, Lc, ic)) { double tv = Lb; Lb = Lc; Lc = tv; int ti = ib; ib = ic; ic = ti; }
            if (!better(La, ia, Lb, ib)) { double tv = La; La = Lb; Lb = tv; int ti = ia; ia = ib; ib = ti; }
            iA = ia; iB = ib;
        }

        const float pA = __shfl(p, iA);
        const float pB = __shfl(p, iB);
        const float pa_ = pA / s;
        const float pb_ = pB / s;
        const float inv = 1.0f / (pa_ + pb_ + 1e-9f);

        if (lane == 0) {
            const size_t tg2 = (size_t)tok;
            outw[tg2 * 2]     = pa_ * inv;
            outw[tg2 * 2 + 1] = pb_ * inv;
            outi[tg2 * 2]     = (float)iA;
            outi[tg2 * 2 + 1] = (float)iB;
        }
    }
}

extern "C" void kernel_launch(void* const* d_in, const int* in_sizes, int n_in,
                              void* d_out, int out_size, void* d_ws, size_t ws_size,
                              hipStream_t stream) {
    const float* x = (const float*)d_in[0];
    const float* W = (const float*)d_in[1];
    float* out = (float*)d_out;

    short* ph   = (short*)d_ws;                              // 256 KB hi panel
    short* pl   = ph + (size_t)NEXP * DDIM;                  // 256 KB lo panel
    float* part = (float*)(pl + (size_t)NEXP * DDIM);        // 8 x 4 MB partials

    prep_w<<<NEXP * DDIM / 8 / 256, 256, 0, stream>>>(W, ph, pl);
    gate_partial<<<NBLK1, 256, 0, stream>>>(x, ph, pl, part);
    router_reduce<<<T_TOKENS / 32, 256, 0, stream>>>(part, x, W, out);
}

// Round 11
// 110.289 us; speedup vs baseline: 1.0288x; 1.0288x over previous
//
#include <hip/hip_runtime.h>
#include <hip/hip_bf16.h>
#include <hip/hip_fp16.h>
#include <math.h>

#define T_TOKENS 16384
#define DDIM 2048
#define NEXP 64
#define REFINE_TAU 4e-3f
#define BLK_TOK 32
#define NBLK (T_TOKENS / BLK_TOK)   // 512 blocks
#define NCH (DDIM / 64)             // 32 chunks of 64 k
#define LGS 66                      // logits LDS stride

typedef _Float16 f16x8 __attribute__((ext_vector_type(8)));
typedef float f32x4 __attribute__((ext_vector_type(4)));

__device__ __forceinline__ void gload_lds16(const void* g, void* l) {
    __builtin_amdgcn_global_load_lds(
        (const __attribute__((address_space(1))) void*)g,
        (__attribute__((address_space(3))) void*)l, 16, 0, 0);
}

// ---------------- Kernel 0: W fp32 -> fp16 fragment-ordered panel ----------------
// Element (expert r, k) -> pw[((g*64 + ks)*64 + lane)*8 + j], g=r>>4, ks=k>>5,
// lane=((k>>3)&3)*16 + (r&15), j=k&7.  (B-frag mapping verified R4-R10.)
__global__ __launch_bounds__(256)
void prep_w(const float* __restrict__ W, _Float16* __restrict__ pw) {
    const int t  = blockIdx.x * 256 + threadIdx.x;   // 0..16383
    const int r  = t >> 8;
    const int kc = (t & 255) * 8;
    const float* wp = &W[(size_t)r * DDIM + kc];
    const float4 a = *(const float4*)wp;
    const float4 b = *(const float4*)(wp + 4);
    const float f[8] = { a.x, a.y, a.z, a.w, b.x, b.y, b.z, b.w };
    f16x8 h;
#pragma unroll
    for (int j = 0; j < 8; ++j) h[j] = (_Float16)f[j];   // RNE
    const int g = r >> 4, ks = kc >> 5;
    const int lane = (((kc >> 3) & 3) << 4) + (r & 15);
    *(f16x8*)&pw[(((size_t)g * 64 + ks) * 64 + lane) * 8] = h;
}

// ---------------- Kernel 1: m97-style gate GEMM + fused top-2 ----------------
__device__ __forceinline__ bool better(double va, int ia, double vb, int ib) {
    return (va > vb) || (va == vb && ia < ib);
}
__device__ __forceinline__ double dot_f64(const float* __restrict__ xrow,
                                          const float* __restrict__ wr, int lane) {
    double sd = 0.0;
    for (int d = lane; d < DDIM; d += 64)
        sd = fma((double)xrow[d], (double)wr[d], sd);
#pragma unroll
    for (int off = 32; off >= 1; off >>= 1) sd += __shfl_xor(sd, off);
    return sd;
}

__global__ __launch_bounds__(256)
void gate_fused(const float* __restrict__ x,
                const _Float16* __restrict__ pw,
                const float* __restrict__ W,
                float* __restrict__ out) {
    // A: 32 tok x 64 k fp32, 256B rows, XOR-swizzled (byte ^= (tok&7)<<4)
    __shared__ float    xa[2][2048];     // 2 x 8 KB
    // B: 8 frags (g,ks) x 64 lanes x 16B, linear
    __shared__ _Float16 bb[2][4096];     // 2 x 8 KB
    __shared__ float    lg[BLK_TOK * LGS];  // 8.25 KB

    const int tid  = threadIdx.x;
    const int lane = tid & 63;
    const int w    = tid >> 6;     // 0..3
    const int tg   = w >> 1;       // token group (16 tok)
    const int eg   = w & 1;        // expert group (32 exp)
    const int tokb = blockIdx.x * BLK_TOK;

    // ---- staging: 16 x 1KB pieces/chunk; wave w issues A pieces {2w,2w+1}, B {2w,2w+1} ----
    // A piece p: rows 4p..4p+3. LDS byte b = p*1024 + lane*16 -> tok=4p+(lane>>4),
    // swizzled col (lane&15)*16 -> actual koff = col ^ ((tok&7)<<4). Source is
    // per-lane pre-swizzled so the LINEAR LDS write yields the swizzled layout.
    const int pA0 = 2 * w;
    const int tokA0 = 4 * pA0 + (lane >> 4);
    const int tokA1 = tokA0 + 4;
    const int koffA0 = ((lane & 15) * 16) ^ ((tokA0 & 7) << 4);
    const int koffA1 = ((lane & 15) * 16) ^ ((tokA1 & 7) << 4);
    const char* xsrc0 = (const char*)x + (size_t)(tokb + tokA0) * (DDIM * 4) + koffA0;
    const char* xsrc1 = (const char*)x + (size_t)(tokb + tokA1) * (DDIM * 4) + koffA1;
    // B piece q = 2w+i: g=q>>1, ks=q&1; src = pw[((g*64 + 2c+ks)*64 + lane)*8]

#define STAGE(buf, c) do { \
    gload_lds16(xsrc0 + (size_t)(c) * 256, (char*)&xa[buf][0] + pA0 * 1024); \
    gload_lds16(xsrc1 + (size_t)(c) * 256, (char*)&xa[buf][0] + (pA0 + 1) * 1024); \
    _Pragma("unroll") \
    for (int i_ = 0; i_ < 2; ++i_) { \
        const int q_ = 2 * w + i_; \
        const int g_ = q_ >> 1, ks_ = q_ & 1; \
        gload_lds16(&pw[(((size_t)g_ * 64 + 2 * (c) + ks_) * 64 + lane) * 8], \
                    (char*)&bb[buf][0] + q_ * 1024); \
    } \
} while (0)

    f32x4 acc[2] = { {0.f, 0.f, 0.f, 0.f}, {0.f, 0.f, 0.f, 0.f} };

    // A-frag read geometry: lane holds A[row=lane&15][k=(lane>>4)*8+j]
    const int atok = tg * 16 + (lane & 15);
    const int aswz = ((atok & 7) << 4);

    STAGE(0, 0);
    __syncthreads();     // chunk 0 landed (vmcnt(0) before barrier)

#pragma unroll 1
    for (int c = 0; c < NCH; ++c) {
        const int buf = c & 1;
        if (c + 1 < NCH) STAGE(buf ^ 1, c + 1);   // in flight under compute

#pragma unroll
        for (int ks = 0; ks < 2; ++ks) {
            const int b0 = atok * 256 + ks * 128 + (lane >> 4) * 32;
            const int a0 = b0 ^ aswz;
            const int a1 = (b0 + 16) ^ aswz;
            const f32x4 v0 = *(const f32x4*)((const char*)&xa[buf][0] + a0);
            const f32x4 v1 = *(const f32x4*)((const char*)&xa[buf][0] + a1);
            f16x8 af;
            af[0] = (_Float16)v0[0]; af[1] = (_Float16)v0[1];
            af[2] = (_Float16)v0[2]; af[3] = (_Float16)v0[3];
            af[4] = (_Float16)v1[0]; af[5] = (_Float16)v1[1];
            af[6] = (_Float16)v1[2]; af[7] = (_Float16)v1[3];
            const f16x8 bf0 = *(const f16x8*)((const char*)&bb[buf][0]
                                + ((2 * eg + 0) * 2 + ks) * 1024 + lane * 16);
            const f16x8 bf1 = *(const f16x8*)((const char*)&bb[buf][0]
                                + ((2 * eg + 1) * 2 + ks) * 1024 + lane * 16);
            acc[0] = __builtin_amdgcn_mfma_f32_16x16x32_f16(af, bf0, acc[0], 0, 0, 0);
            acc[1] = __builtin_amdgcn_mfma_f32_16x16x32_f16(af, bf1, acc[1], 0, 0, 0);
        }
        __syncthreads();   // drains next-chunk loads + LDS ops; buf^1 ready
    }
#undef STAGE

    // ---- logits -> LDS (C layout: col=lane&15=expert, row=(lane>>4)*4+j=token; m89-verified) ----
#pragma unroll
    for (int n = 0; n < 2; ++n)
#pragma unroll
        for (int j = 0; j < 4; ++j) {
            const int tokr = tg * 16 + ((lane >> 4) << 2) + j;
            const int ecol = eg * 32 + n * 16 + (lane & 15);
            lg[tokr * LGS + ecol] = acc[n][j];
        }
    __syncthreads();

    // ---- fused epilogue: each wave owns 8 tokens (verified structure) ----
    float* __restrict__ outw = out;
    float* __restrict__ outi = out + (size_t)T_TOKENS * 2;

#pragma unroll 1
    for (int t = 0; t < 8; ++t) {
        const int lt  = w * 8 + t;
        const int tok = tokb + lt;
        const float l = lg[lt * LGS + lane];

        float v1 = l; int i1 = lane;
#pragma unroll
        for (int off = 32; off >= 1; off >>= 1) {
            const float ov = __shfl_xor(v1, off);
            const int   oi = __shfl_xor(i1, off);
            if (ov > v1 || (ov == v1 && oi < i1)) { v1 = ov; i1 = oi; }
        }
        float v2 = (lane == i1) ? -INFINITY : l; int i2 = lane;
#pragma unroll
        for (int off = 32; off >= 1; off >>= 1) {
            const float ov = __shfl_xor(v2, off);
            const int   oi = __shfl_xor(i2, off);
            if (ov > v2 || (ov == v2 && oi < i2)) { v2 = ov; i2 = oi; }
        }
        float v3 = (lane == i1 || lane == i2) ? -INFINITY : l; int i3 = lane;
#pragma unroll
        for (int off = 32; off >= 1; off >>= 1) {
            const float ov = __shfl_xor(v3, off);
            const int   oi = __shfl_xor(i3, off);
            if (ov > v3 || (ov == v3 && oi < i3)) { v3 = ov; i3 = oi; }
        }

        const float p = expf(l - v1);
        float s = p;
#pragma unroll
        for (int off = 32; off >= 1; off >>= 1) s += __shfl_xor(s, off);

        int iA = i1, iB = i2;
        if ((v1 - v2) < REFINE_TAU || (v2 - v3) < REFINE_TAU) {
            const float* __restrict__ xrow = x + (size_t)tok * DDIM;
            double La = dot_f64(xrow, W + (size_t)i1 * DDIM, lane);
            double Lb = dot_f64(xrow, W + (size_t)i2 * DDIM, lane);
            double Lc = dot_f64(xrow, W + (size_t)i3 * DDIM, lane);
            int ia = i1, ib = i2, ic = i3;
            if (!better(La, ia, Lb, ib)) { double tv = La; La = Lb; Lb = tv; int ti = ia; ia = ib; ib = ti; }
            if (!better(Lb, ib, Lc, ic)) { double tv = Lb; Lb = Lc; Lc = tv; int ti = ib; ib = ic; ic = ti; }
            if (!better(La, ia, Lb, ib)) { double tv = La; La = Lb; Lb = tv; int ti = ia; ia = ib; ib = ti; }
            iA = ia; iB = ib;
        }

        const float pA = __shfl(p, iA);
        const float pB = __shfl(p, iB);
        const float pa_ = pA / s;
        const float pb_ = pB / s;
        const float inv = 1.0f / (pa_ + pb_ + 1e-9f);

        if (lane == 0) {
            const size_t tg2 = (size_t)tok;
            outw[tg2 * 2]     = pa_ * inv;
            outw[tg2 * 2 + 1] = pb_ * inv;
            outi[tg2 * 2]     = (float)iA;
            outi[tg2 * 2 + 1] = (float)iB;
        }
    }
}

extern "C" void kernel_launch(void* const* d_in, const int* in_sizes, int n_in,
                              void* d_out, int out_size, void* d_ws, size_t ws_size,
                              hipStream_t stream) {
    const float* x = (const float*)d_in[0];
    const float* W = (const float*)d_in[1];
    float* out = (float*)d_out;
    _Float16* pw = (_Float16*)d_ws;                 // 256 KB fp16 panel

    prep_w<<<NEXP * DDIM / 8 / 256, 256, 0, stream>>>(W, pw);
    gate_fused<<<NBLK, 256, 0, stream>>>(x, pw, W, out);
}

// Round 12
// 90.347 us; speedup vs baseline: 1.2559x; 1.2207x over previous
//
#include <hip/hip_runtime.h>
#include <hip/hip_bf16.h>
#include <hip/hip_fp16.h>
#include <math.h>

#define T_TOKENS 16384
#define DDIM 2048
#define NEXP 64
#define REFINE_TAU 4e-3f
#define KSL 4                        // K slices (one per block-column)
#define KPS (DDIM / KSL)             // 512 k per slice
#define NKS (KPS / 32)               // 16 ksteps of 32 k
#define BLK_TOK 128                  // 8 waves x 16 tokens
#define NBLK ((T_TOKENS / BLK_TOK) * KSL)   // 512 blocks

typedef _Float16 f16x8 __attribute__((ext_vector_type(8)));
typedef float f32x4 __attribute__((ext_vector_type(4)));

__device__ __forceinline__ void gload_lds16(const void* g, void* l) {
    __builtin_amdgcn_global_load_lds(
        (const __attribute__((address_space(1))) void*)g,
        (__attribute__((address_space(3))) void*)l, 16, 0, 0);
}

// ---------------- Kernel 0: W fp32 -> fp16 fragment panel, slice-major ----------------
// (r,k) -> pw[((((slice*4)+g)*16 + ks)*64 + lane)*8 + j]; slice=k>>9, g=r>>4,
// ks=(k>>5)&15, lane=((k>>3)&3)*16 + (r&15), j=k&7.  (frag mapping verified R4-R11)
__global__ __launch_bounds__(256)
void prep_w(const float* __restrict__ W, _Float16* __restrict__ pw) {
    const int t  = blockIdx.x * 256 + threadIdx.x;   // 0..16383
    const int r  = t >> 8;
    const int kc = (t & 255) * 8;
    const float* wp = &W[(size_t)r * DDIM + kc];
    const float4 a = *(const float4*)wp;
    const float4 b = *(const float4*)(wp + 4);
    const float f[8] = { a.x, a.y, a.z, a.w, b.x, b.y, b.z, b.w };
    f16x8 h;
#pragma unroll
    for (int j = 0; j < 8; ++j) h[j] = (_Float16)f[j];
    const int slice = kc >> 9;
    const int ks    = (kc >> 5) & 15;
    const int g     = r >> 4;
    const int lane  = (((kc >> 3) & 3) << 4) + (r & 15);
    pw += ((((size_t)slice * 4 + g) * 16 + ks) * 64 + lane) * 8;
    *(f16x8*)pw = h;
}

// ---------------- Kernel 1: LDS-panel barrier-free gate GEMM -> fp32 partials ----------------
__global__ __launch_bounds__(512, 4)
void gate_partial(const float* __restrict__ x,
                  const _Float16* __restrict__ pw,
                  float* __restrict__ part) {
    __shared__ _Float16 bp[4 * 16 * 64 * 8];     // 64 KB -> occupancy LDS-bound at 2 blocks/CU

    const int tid   = threadIdx.x;
    const int lane  = tid & 63;
    const int w     = tid >> 6;                  // token-tile 0..7
    const int bx    = blockIdx.x;
    const int slice = bx & 3;
    const int tokb  = (bx >> 2) * BLK_TOK;

    // ---- stage this slice's 64 KB panel into LDS (8 x 1KB per wave) ----
    {
        const char* src = (const char*)pw + (size_t)slice * 65536 + w * 1024 + lane * 16;
        char* dst = (char*)&bp[0] + w * 1024;    // wave-uniform base; HW adds lane*16
#pragma unroll
        for (int it = 0; it < 8; ++it)
            gload_lds16(src + it * 8192, dst + it * 8192);
    }

    // ---- x A-frag source: token = tokb + w*16 + (lane&15), k = slice*512 + ks*32 + (lane>>4)*8 ----
    const int atok = tokb + w * 16 + (lane & 15);
    const char* xsrc = (const char*)x
        + ((size_t)atok * DDIM + slice * KPS + ((lane >> 4) << 3)) * 4;

    float4 xb0[4], xb1[4];                        // 4-step rolling buffer (static slots)
#define LOADX(s, ks) do { \
    xb0[s] = *(const float4*)(xsrc + (ks) * 128); \
    xb1[s] = *(const float4*)(xsrc + (ks) * 128 + 16); \
} while (0)

    LOADX(0, 0); LOADX(1, 1); LOADX(2, 2); LOADX(3, 3);
    __syncthreads();                              // one barrier: panel + prefetch landed

    f32x4 acc[4] = { {0,0,0,0}, {0,0,0,0}, {0,0,0,0}, {0,0,0,0} };

#pragma unroll
    for (int ks = 0; ks < NKS; ++ks) {
        const int s = ks & 3;
        f16x8 af;
        af[0] = (_Float16)xb0[s].x; af[1] = (_Float16)xb0[s].y;
        af[2] = (_Float16)xb0[s].z; af[3] = (_Float16)xb0[s].w;
        af[4] = (_Float16)xb1[s].x; af[5] = (_Float16)xb1[s].y;
        af[6] = (_Float16)xb1[s].z; af[7] = (_Float16)xb1[s].w;
#pragma unroll
        for (int g = 0; g < 4; ++g) {
            const f16x8 bf = *(const f16x8*)&bp[(((g * 16 + ks) * 64) + lane) * 8];
            acc[g] = __builtin_amdgcn_mfma_f32_16x16x32_f16(af, bf, acc[g], 0, 0, 0);
        }
        if (ks + 4 < NKS) LOADX(s, ks + 4);       // 4-iter issue-to-use distance
    }
#undef LOADX

    // ---- partial store: C row=(lane>>4)*4+j = token-in-tile, col=lane&15 = expert-in-group ----
#pragma unroll
    for (int g = 0; g < 4; ++g)
#pragma unroll
        for (int j = 0; j < 4; ++j) {
            const int tok = tokb + w * 16 + ((lane >> 4) << 2) + j;
            part[((size_t)slice * T_TOKENS + tok) * NEXP + g * 16 + (lane & 15)] = acc[g][j];
        }
}

// ---------------- Kernel 2: K-reduce + softmax + top-2 (R10-verified) ----------------
__device__ __forceinline__ bool better(double va, int ia, double vb, int ib) {
    return (va > vb) || (va == vb && ia < ib);
}
__device__ __forceinline__ double dot_f64(const float* __restrict__ xrow,
                                          const float* __restrict__ wr, int lane) {
    double sd = 0.0;
    for (int d = lane; d < DDIM; d += 64)
        sd = fma((double)xrow[d], (double)wr[d], sd);
#pragma unroll
    for (int off = 32; off >= 1; off >>= 1) sd += __shfl_xor(sd, off);
    return sd;
}

__global__ __launch_bounds__(256)
void router_reduce(const float* __restrict__ part,
                   const float* __restrict__ x,
                   const float* __restrict__ W,
                   float* __restrict__ out) {
    const int tid  = threadIdx.x;
    const int lane = tid & 63;
    const int w    = tid >> 6;
    const int tok0 = (blockIdx.x * 4 + w) * 8;

    float* __restrict__ outw = out;
    float* __restrict__ outi = out + (size_t)T_TOKENS * 2;

#pragma unroll 1
    for (int t = 0; t < 8; ++t) {
        const int tok = tok0 + t;
        float l = 0.f;
#pragma unroll
        for (int s = 0; s < KSL; ++s)
            l += part[((size_t)s * T_TOKENS + tok) * NEXP + lane];

        float v1 = l; int i1 = lane;
#pragma unroll
        for (int off = 32; off >= 1; off >>= 1) {
            const float ov = __shfl_xor(v1, off);
            const int   oi = __shfl_xor(i1, off);
            if (ov > v1 || (ov == v1 && oi < i1)) { v1 = ov; i1 = oi; }
        }
        float v2 = (lane == i1) ? -INFINITY : l; int i2 = lane;
#pragma unroll
        for (int off = 32; off >= 1; off >>= 1) {
            const float ov = __shfl_xor(v2, off);
            const int   oi = __shfl_xor(i2, off);
            if (ov > v2 || (ov == v2 && oi < i2)) { v2 = ov; i2 = oi; }
        }
        float v3 = (lane == i1 || lane == i2) ? -INFINITY : l; int i3 = lane;
#pragma unroll
        for (int off = 32; off >= 1; off >>= 1) {
            const float ov = __shfl_xor(v3, off);
            const int   oi = __shfl_xor(i3, off);
            if (ov > v3 || (ov == v3 && oi < i3)) { v3 = ov; i3 = oi; }
        }

        const float p = expf(l - v1);
        float s = p;
#pragma unroll
        for (int off = 32; off >= 1; off >>= 1) s += __shfl_xor(s, off);

        int iA = i1, iB = i2;
        if ((v1 - v2) < REFINE_TAU || (v2 - v3) < REFINE_TAU) {
            const float* __restrict__ xrow = x + (size_t)tok * DDIM;
            double La = dot_f64(xrow, W + (size_t)i1 * DDIM, lane);
            double Lb = dot_f64(xrow, W + (size_t)i2 * DDIM, lane);
            double Lc = dot_f64(xrow, W + (size_t)i3 * DDIM, lane);
            int ia = i1, ib = i2, ic = i3;
            if (!better(La, ia, Lb, ib)) { double tv = La; La = Lb; Lb = tv; int ti = ia; ia = ib; ib = ti; }
            if (!better(Lb, ib, Lc, ic)) { double tv = Lb; Lb = Lc; Lc = tv; int ti = ib; ib = ic; ic = ti; }
            if (!better(La, ia, Lb, ib)) { double tv = La; La = Lb; Lb = tv; int ti = ia; ia = ib; ib = ti; }
            iA = ia; iB = ib;
        }

        const float pA = __shfl(p, iA);
        const float pB = __shfl(p, iB);
        const float pa_ = pA / s;
        const float pb_ = pB / s;
        const float inv = 1.0f / (pa_ + pb_ + 1e-9f);

        if (lane == 0) {
            const size_t tg2 = (size_t)tok;
            outw[tg2 * 2]     = pa_ * inv;
            outw[tg2 * 2 + 1] = pb_ * inv;
            outi[tg2 * 2]     = (float)iA;
            outi[tg2 * 2 + 1] = (float)iB;
        }
    }
}

extern "C" void kernel_launch(void* const* d_in, const int* in_sizes, int n_in,
                              void* d_out, int out_size, void* d_ws, size_t ws_size,
                              hipStream_t stream) {
    const float* x = (const float*)d_in[0];
    const float* W = (const float*)d_in[1];
    float* out = (float*)d_out;

    _Float16* pw  = (_Float16*)d_ws;                         // 256 KB fp16 frag panel
    float*    prt = (float*)((char*)d_ws + 262144);          // 4 x 4 MB partials

    prep_w<<<NEXP * DDIM / 8 / 256, 256, 0, stream>>>(W, pw);
    gate_partial<<<NBLK, 512, 0, stream>>>(x, pw, prt);
    router_reduce<<<T_TOKENS / 32, 256, 0, stream>>>(prt, x, W, out);
}